// Round 4
// baseline (175.988 us; speedup 1.0000x reference)
//
#include <hip/hip_runtime.h>
#include <stdint.h>

#define B  8
#define TE 2048
#define TD 256
#define H  128

// ---------- kernel 1: register-tiled GEMM (unchanged) ----------
// E written t-tiled: EgT[b][tb][k][tl]  (tb = t>>6, tl = t&63); F row-major [b][j][k].
#define FMA4(acc, s, wv) \
  acc.x += (s)*(wv).x; acc.y += (s)*(wv).y; acc.z += (s)*(wv).z; acc.w += (s)*(wv).w

__global__ __launch_bounds__(256) void proj_kernel(
    const float* __restrict__ enc, const float* __restrict__ dec,
    const float* __restrict__ Wa,  const float* __restrict__ Ua,
    float* __restrict__ EgT, float* __restrict__ Fg) {
  __shared__ float Ls[16 * 132];
  const float C2 = 2.8853900817779268f;  // 2*log2(e):  exp(2x) = exp2(C2*x)
  int tid = threadIdx.x;
  int bid = blockIdx.x;
  bool isE = (bid < 1024);
  int rbase = (isE ? bid : bid - 1024) * 16;
  const float* in = isE ? enc : dec;
  const float* Mg = isE ? Wa : Ua;
  int hq = tid & 31, rq = tid >> 5;
  int h0 = hq * 4, r0 = rq * 2;
  const float* rowp = in + (size_t)(rbase + r0) * H;
  const float* wp = Mg + h0;
  float4 a0{0,0,0,0}, a1{0,0,0,0};
  #pragma unroll 2
  for (int kb = 0; kb < 32; ++kb) {
    float4 rv0 = *(const float4*)(rowp + kb * 4);
    float4 rv1 = *(const float4*)(rowp + H + kb * 4);
    float4 w0 = *(const float4*)(wp + (size_t)(4 * kb + 0) * H);
    float4 w1 = *(const float4*)(wp + (size_t)(4 * kb + 1) * H);
    float4 w2 = *(const float4*)(wp + (size_t)(4 * kb + 2) * H);
    float4 w3 = *(const float4*)(wp + (size_t)(4 * kb + 3) * H);
    FMA4(a0, rv0.x, w0); FMA4(a0, rv0.y, w1); FMA4(a0, rv0.z, w2); FMA4(a0, rv0.w, w3);
    FMA4(a1, rv1.x, w0); FMA4(a1, rv1.y, w1); FMA4(a1, rv1.z, w2); FMA4(a1, rv1.w, w3);
  }
  float4 e0, e1;
  e0.x = __builtin_amdgcn_exp2f(a0.x * C2); e0.y = __builtin_amdgcn_exp2f(a0.y * C2);
  e0.z = __builtin_amdgcn_exp2f(a0.z * C2); e0.w = __builtin_amdgcn_exp2f(a0.w * C2);
  e1.x = __builtin_amdgcn_exp2f(a1.x * C2); e1.y = __builtin_amdgcn_exp2f(a1.y * C2);
  e1.z = __builtin_amdgcn_exp2f(a1.z * C2); e1.w = __builtin_amdgcn_exp2f(a1.w * C2);
  if (isE) {
    *(float4*)&Ls[(r0 + 0) * 132 + h0] = e0;
    *(float4*)&Ls[(r0 + 1) * 132 + h0] = e1;
    __syncthreads();
    int b_e = rbase >> 11, t_in = rbase & 2047;
    int tb = t_in >> 6, toff = t_in & 63;
    float* dst = EgT + ((size_t)(b_e * 32 + tb) * 128) * 64 + toff;
    #pragma unroll
    for (int jj = 0; jj < 8; ++jj) {
      int idx = jj * 256 + tid;
      int r = idx & 15, k = idx >> 4;
      dst[(size_t)k * 64 + r] = Ls[r * 132 + k];
    }
  } else {
    int b_f = rbase >> 8, j_in = rbase & 255;
    float* dst = Fg + ((size_t)(b_f * TD + j_in + r0)) * H + h0;
    *(float4*)(dst + 0 * H) = e0;
    *(float4*)(dst + 1 * H) = e1;
  }
}

// ---------- kernel 2: fused (R14: 4k-group rcp, 2 blocks/CU for idle-fill) ----------
// 512 blocks x 512 thr x 4 j. Per CU: 2 independent blocks -> one block's barriers /
// softmax / tail overlap the other's phase-1/3 compute. rcp count halved via
// common-denominator 4-k groups (exact algebra; P >= 1, no underflow).
__global__ __launch_bounds__(512, 4) void fused_kernel(
    const float* __restrict__ EgT, const float* __restrict__ Fg,
    const float* __restrict__ Va,  const float* __restrict__ enc,
    float* __restrict__ oute, float* __restrict__ outc) {
  __shared__ float S[4 * 2048];    // 32 KB: scores [j][t] -> e [j][t] -> c-partials
  __shared__ float red[16];
  int tid = threadIdx.x;
  int bid = blockIdx.x;
  int b = bid & 7, jt = bid >> 3;  // consecutive ids round-robin XCDs -> XCD pinned to b
  int j0 = jt * 4;
  int lane = tid & 63, w = tid >> 6;   // w in 0..7
  const float4* vp = (const float4*)Va;
  float V1 = 0.f;
  #pragma unroll
  for (int q = 0; q < 32; ++q) { float4 v = vp[q]; V1 += v.x + v.y + v.z + v.w; }

  // ---- phase 1: scores[j][t] = V1 - 2*sum_k v_k/(E[t,k]*F[j,k]+1) into LDS ----
  const float4* Fp = (const float4*)(Fg + (size_t)(b * TD + j0) * H);
  const float* Ep[4];
  #pragma unroll
  for (int it = 0; it < 4; ++it)       // t-tiles w, w+8, w+16, w+24
    Ep[it] = EgT + ((size_t)(b * 32 + w + 8 * it) * 128) * 64 + lane;
  float s[4][4];
  #pragma unroll
  for (int it = 0; it < 4; ++it)
    #pragma unroll
    for (int j = 0; j < 4; ++j) s[it][j] = 0.f;
  float eka[8], ekb[8];

  // 8 independent b32 loads, imm offsets; consumed one (kc,it)-step later
#define LOADE(dst, base, off)                                        \
  { const float* _p = (base) + (off);                                \
    dst[0] = _p[0];   dst[1] = _p[64];  dst[2] = _p[128];            \
    dst[3] = _p[192]; dst[4] = _p[256]; dst[5] = _p[320];            \
    dst[6] = _p[384]; dst[7] = _p[448]; }

  // 4-k common-denominator: v.x/d0+v.y/d1+v.z/d2+v.w/d3 with ONE rcp.
  // P = d0*d1*d2*d3 >= 1 (d = E*F+1 >= 1): no underflow; overflow ~11-sigma event,
  // and its failure mode (rcp(inf)=0) matches the true ~0 contribution.
#define UNIT4(accres, e0_, e1_, e2_, e3_, fv, vv)                         \
  {                                                                       \
    float d0 = fmaf(e0_, fv.x, 1.0f), d1 = fmaf(e1_, fv.y, 1.0f);        \
    float d2 = fmaf(e2_, fv.z, 1.0f), d3 = fmaf(e3_, fv.w, 1.0f);        \
    float p01 = d0 * d1, p23 = d2 * d3;                                   \
    float rP = __builtin_amdgcn_rcpf(p01 * p23);                          \
    float n01 = vv.x * d1 + vv.y * d0;                                    \
    float n23 = vv.z * d3 + vv.w * d2;                                    \
    accres = fmaf(n01 * p23 + n23 * p01, rP, accres);                     \
  }

  LOADE(eka, Ep[0], 0);                      // prologue: step (kc=0, it=0)
  for (int kc = 0; kc < 16; ++kc) {
    float4 f0[4], f1[4];                     // block-uniform -> SGPR
    const float4* fpc = Fp + kc * 2;
    #pragma unroll
    for (int j = 0; j < 4; ++j) {
      f0[j] = fpc[j * 32];
      f1[j] = fpc[j * 32 + 1];
    }
    float4 v0 = vp[kc * 2], v1 = vp[kc * 2 + 1];
    #pragma unroll
    for (int it = 0; it < 4; ++it) {
      // prefetch next step's E (it+1, or next kc's it=0; kc=15,it=3 prefetches
      // one tile beyond Ep[0]+15*512 -- in-bounds (max tile index 232 < 256))
      if (it < 3) { LOADE(ekb, Ep[it + 1], kc * 512); }
      else        { LOADE(ekb, Ep[0], (kc + 1) * 512); }
      #pragma unroll
      for (int j = 0; j < 4; ++j) {
        UNIT4(s[it][j], eka[0], eka[1], eka[2], eka[3], f0[j], v0);
        UNIT4(s[it][j], eka[4], eka[5], eka[6], eka[7], f1[j], v1);
      }
      #pragma unroll
      for (int q = 0; q < 8; ++q) eka[q] = ekb[q];
    }
  }
  #pragma unroll
  for (int it = 0; it < 4; ++it) {
    int t = (w + 8 * it) * 64 + lane;
    S[0 * 2048 + t] = V1 - 2.0f * s[it][0];  // bank = lane%32: 2-way (free)
    S[1 * 2048 + t] = V1 - 2.0f * s[it][1];
    S[2 * 2048 + t] = V1 - 2.0f * s[it][2];
    S[3 * 2048 + t] = V1 - 2.0f * s[it][3];
  }
  __syncthreads();

  // ---- phase 2: softmax per j-row (2 waves per j); e overwrites S in place ----
  int j = w >> 1, half = w & 1;
  int tb2 = half * 1024 + lane;
  float x[16];
  #pragma unroll
  for (int q = 0; q < 16; ++q) x[q] = S[j * 2048 + tb2 + q * 64];
  float m = x[0];
  #pragma unroll
  for (int q = 1; q < 16; ++q) m = fmaxf(m, x[q]);
  #pragma unroll
  for (int off = 32; off > 0; off >>= 1) m = fmaxf(m, __shfl_xor(m, off));
  if (lane == 0) red[w] = m;
  __syncthreads();                             // also: all raw-S reads complete
  m = fmaxf(red[j * 2], red[j * 2 + 1]);
  const float L2E = 1.4426950408889634f;
  float sum = 0.f;
  #pragma unroll
  for (int q = 0; q < 16; ++q) {
    x[q] = __builtin_amdgcn_exp2f((x[q] - m) * L2E);
    sum += x[q];
  }
  #pragma unroll
  for (int off = 32; off > 0; off >>= 1) sum += __shfl_xor(sum, off);
  if (lane == 0) red[8 + w] = sum;
  __syncthreads();
  float inv = 1.0f / (red[8 + j * 2] + red[8 + j * 2 + 1]);
  float* orow = oute + (size_t)(b * TD + j0 + j) * TE;
  #pragma unroll
  for (int q = 0; q < 16; ++q) {
    float e = x[q] * inv;
    int t = tb2 + q * 64;
    orow[t] = e;                               // coalesced 256 B/instr
    S[j * 2048 + t] = e;                       // in place: same slot it read
  }
  __syncthreads();

  // ---- phase 3: c[j][h] = sum_t e[j][t]*enc[t][h]; 16 slices x 128 t, pipelined ----
  int hq = tid & 31, slice = tid >> 5;         // h = hq*4; t in [slice*128, ...+128)
  const float* encp = enc + ((size_t)b * TE + slice * 128) * H + hq * 4;
  const float* Se = S + slice * 128;           // + j*2048 + t (b128, 2-addr broadcast)
  float4 ac0{0,0,0,0}, ac1{0,0,0,0}, ac2{0,0,0,0}, ac3{0,0,0,0};
  float4 evA0, evA1, evA2, evA3, evB0, evB1, evB2, evB3;

#define LOADENC(d0, d1, d2, d3, t0)                         \
  d0 = *(const float4*)(encp + (size_t)(t0 + 0) * H);       \
  d1 = *(const float4*)(encp + (size_t)(t0 + 1) * H);       \
  d2 = *(const float4*)(encp + (size_t)(t0 + 2) * H);       \
  d3 = *(const float4*)(encp + (size_t)(t0 + 3) * H);

#define GROUP(t0, ex, ey, ez, ew)                                            \
  {                                                                          \
    float4 E0 = *(const float4*)&Se[0 * 2048 + (t0)];                        \
    float4 E1 = *(const float4*)&Se[1 * 2048 + (t0)];                        \
    float4 E2 = *(const float4*)&Se[2 * 2048 + (t0)];                        \
    float4 E3 = *(const float4*)&Se[3 * 2048 + (t0)];                        \
    FMA4(ac0, E0.x, ex); FMA4(ac0, E0.y, ey); FMA4(ac0, E0.z, ez); FMA4(ac0, E0.w, ew); \
    FMA4(ac1, E1.x, ex); FMA4(ac1, E1.y, ey); FMA4(ac1, E1.z, ez); FMA4(ac1, E1.w, ew); \
    FMA4(ac2, E2.x, ex); FMA4(ac2, E2.y, ey); FMA4(ac2, E2.z, ez); FMA4(ac2, E2.w, ew); \
    FMA4(ac3, E3.x, ex); FMA4(ac3, E3.y, ey); FMA4(ac3, E3.z, ez); FMA4(ac3, E3.w, ew); \
  }

  LOADENC(evA0, evA1, evA2, evA3, 0);
  #pragma unroll
  for (int tb = 0; tb < 128; tb += 8) {
    LOADENC(evB0, evB1, evB2, evB3, tb + 4);
    GROUP(tb, evA0, evA1, evA2, evA3);
    if (tb < 120) { LOADENC(evA0, evA1, evA2, evA3, tb + 8); }
    GROUP(tb + 4, evB0, evB1, evB2, evB3);
  }
  __syncthreads();                             // all e-reads done; reuse S for partials
  if (slice < 8) {                             // wave-uniform (waves 0-3)
    float* dst = &S[slice * 512 + hq * 4];
    *(float4*)(dst + 0 * 128) = ac0; *(float4*)(dst + 1 * 128) = ac1;
    *(float4*)(dst + 2 * 128) = ac2; *(float4*)(dst + 3 * 128) = ac3;
  }
  __syncthreads();
  if (slice >= 8) {                            // waves 4-7: read-modify-add
    float* dst = &S[(slice - 8) * 512 + hq * 4];
    #define RMW(J, AC) { float4 p = *(float4*)(dst + J * 128); \
      p.x += AC.x; p.y += AC.y; p.z += AC.z; p.w += AC.w; \
      *(float4*)(dst + J * 128) = p; }
    RMW(0, ac0) RMW(1, ac1) RMW(2, ac2) RMW(3, ac3)
    #undef RMW
  }
  __syncthreads();
  float r = 0.f;
  #pragma unroll
  for (int sl = 0; sl < 8; ++sl) r += S[sl * 512 + tid];   // stride-1, conflict-free
  outc[(size_t)(b * TD + j0 + (tid >> 7)) * H + (tid & 127)] = r;
}

extern "C" void kernel_launch(void* const* d_in, const int* in_sizes, int n_in,
                              void* d_out, int out_size, void* d_ws, size_t ws_size,
                              hipStream_t stream) {
  (void)in_sizes; (void)n_in; (void)out_size; (void)ws_size;
  const float* enc = (const float*)d_in[0];
  const float* dec = (const float*)d_in[1];
  const float* Wa  = (const float*)d_in[2];
  const float* Ua  = (const float*)d_in[3];
  const float* Va  = (const float*)d_in[4];

  float* ws  = (float*)d_ws;
  float* EgT = ws;                                   // 8 MB  E tiled [b][tb][k][tl]
  float* Fg  = EgT + (size_t)B * TE * H;             // 1 MB  F [b][j][k]
  float* outc = (float*)d_out;                       // c [B,TD,H] fp32
  float* oute = outc + (size_t)B * TD * H;           // e [B,TD,TE] fp32

  proj_kernel<<<dim3(1152), 256, 0, stream>>>(enc, dec, Wa, Ua, EgT, Fg);
  fused_kernel<<<dim3(512), 512, 0, stream>>>(EgT, Fg, Va, enc, oute, outc);
}

// Round 6
// 167.563 us; speedup vs baseline: 1.0503x; 1.0503x over previous
//
#include <hip/hip_runtime.h>
#include <stdint.h>

#define B  8
#define TE 2048
#define TD 256
#define H  128

// ---------- kernel 1: register-tiled GEMM ----------
// E written t-tiled k-paired: EgT[b][tb][k2=64][tl=64][2]  (tb = t>>6, tl = t&63,
// k = 2*k2+half); F row-major [b][j][k].
#define FMA4(acc, s, wv) \
  acc.x += (s)*(wv).x; acc.y += (s)*(wv).y; acc.z += (s)*(wv).z; acc.w += (s)*(wv).w

__global__ __launch_bounds__(256) void proj_kernel(
    const float* __restrict__ enc, const float* __restrict__ dec,
    const float* __restrict__ Wa,  const float* __restrict__ Ua,
    float* __restrict__ EgT, float* __restrict__ Fg) {
  __shared__ float Ls[16 * 132];
  const float C2 = 2.8853900817779268f;  // 2*log2(e):  exp(2x) = exp2(C2*x)
  int tid = threadIdx.x;
  int bid = blockIdx.x;
  bool isE = (bid < 1024);
  int rbase = (isE ? bid : bid - 1024) * 16;
  const float* in = isE ? enc : dec;
  const float* Mg = isE ? Wa : Ua;
  int hq = tid & 31, rq = tid >> 5;
  int h0 = hq * 4, r0 = rq * 2;
  const float* rowp = in + (size_t)(rbase + r0) * H;
  const float* wp = Mg + h0;
  float4 a0{0,0,0,0}, a1{0,0,0,0};
  #pragma unroll 2
  for (int kb = 0; kb < 32; ++kb) {
    float4 rv0 = *(const float4*)(rowp + kb * 4);
    float4 rv1 = *(const float4*)(rowp + H + kb * 4);
    float4 w0 = *(const float4*)(wp + (size_t)(4 * kb + 0) * H);
    float4 w1 = *(const float4*)(wp + (size_t)(4 * kb + 1) * H);
    float4 w2 = *(const float4*)(wp + (size_t)(4 * kb + 2) * H);
    float4 w3 = *(const float4*)(wp + (size_t)(4 * kb + 3) * H);
    FMA4(a0, rv0.x, w0); FMA4(a0, rv0.y, w1); FMA4(a0, rv0.z, w2); FMA4(a0, rv0.w, w3);
    FMA4(a1, rv1.x, w0); FMA4(a1, rv1.y, w1); FMA4(a1, rv1.z, w2); FMA4(a1, rv1.w, w3);
  }
  float4 e0, e1;
  e0.x = __builtin_amdgcn_exp2f(a0.x * C2); e0.y = __builtin_amdgcn_exp2f(a0.y * C2);
  e0.z = __builtin_amdgcn_exp2f(a0.z * C2); e0.w = __builtin_amdgcn_exp2f(a0.w * C2);
  e1.x = __builtin_amdgcn_exp2f(a1.x * C2); e1.y = __builtin_amdgcn_exp2f(a1.y * C2);
  e1.z = __builtin_amdgcn_exp2f(a1.z * C2); e1.w = __builtin_amdgcn_exp2f(a1.w * C2);
  if (isE) {
    // transpose through LDS, emit k-paired: dst[q*128 + tl*2 + half]
    *(float4*)&Ls[(r0 + 0) * 132 + h0] = e0;
    *(float4*)&Ls[(r0 + 1) * 132 + h0] = e1;
    __syncthreads();
    int b_e = rbase >> 11, t_in = rbase & 2047;
    int tb = t_in >> 6, toff = t_in & 63;  // 16-row chunk within the 64-t tile
    float* dst = EgT + (size_t)(b_e * 32 + tb) * 8192 + toff * 2;
    #pragma unroll
    for (int jj = 0; jj < 4; ++jj) {
      int idx = jj * 256 + tid;            // 1024 pairs
      int r = idx & 15, q = idx >> 4;      // r: row in chunk, q: k-pair 0..63
      float2 val{Ls[r * 132 + 2 * q], Ls[r * 132 + 2 * q + 1]};
      *(float2*)(dst + (size_t)q * 128 + r * 2) = val;  // 8B/lane, coalesced
    }
  } else {
    int b_f = rbase >> 8, j_in = rbase & 255;
    float* dst = Fg + ((size_t)(b_f * TD + j_in + r0)) * H + h0;
    *(float4*)(dst + 0 * H) = e0;
    *(float4*)(dst + 1 * H) = e1;
  }
}

// ---------- kernel 2: fused (R15 rerun: 4j x 512thr x 2blk/CU, b64 E loads, copy-free dbuf) ----------
__global__ __launch_bounds__(512, 4) void fused_kernel(
    const float* __restrict__ EgT, const float* __restrict__ Fg,
    const float* __restrict__ Va,  const float* __restrict__ enc,
    float* __restrict__ oute, float* __restrict__ outc) {
  __shared__ float S[4 * 2048];    // 32 KB: scores [j][t] -> e [j][t] -> c-partials
  __shared__ float red[16];
  int tid = threadIdx.x;
  int bid = blockIdx.x;
  int b = bid & 7, jt = bid >> 3;  // consecutive ids round-robin XCDs -> XCD pinned to b
  int j0 = jt * 4;
  int lane = tid & 63, w = tid >> 6;   // w in 0..7
  const float4* vp = (const float4*)Va;
  float V1 = 0.f;
  #pragma unroll
  for (int q = 0; q < 32; ++q) { float4 v = vp[q]; V1 += v.x + v.y + v.z + v.w; }

  // ---- phase 1: scores[j][t] = V1 - 2*sum_k v_k/(E[t,k]*F[j,k]+1) into LDS ----
  const float4* Fp = (const float4*)(Fg + (size_t)(b * TD + j0) * H);
  const float* Ep[4];
  #pragma unroll
  for (int it = 0; it < 4; ++it)       // t-tiles w, w+8, w+16, w+24; lane's pair base
    Ep[it] = EgT + (size_t)(b * 32 + w + 8 * it) * 8192 + lane * 2;
  float s[4][4];
  #pragma unroll
  for (int it = 0; it < 4; ++it)
    #pragma unroll
    for (int j = 0; j < 4; ++j) s[it][j] = 0.f;
  float2 eka[4], ekb[4];

  // 4 independent b64 loads (8 k), imm offsets; consumed 4 UNITs (~224 VALU cyc) later
#define LOADE2(dst, base, off)                                       \
  { const float* _p = (base) + (off);                                \
    dst[0] = *(const float2*)(_p);       dst[1] = *(const float2*)(_p + 128);  \
    dst[2] = *(const float2*)(_p + 256); dst[3] = *(const float2*)(_p + 384); }

  // exact original 2k-pair math (bit-identical to R1/R3)
#define UNIT(acc, ekk, jj)                                                    \
  {                                                                           \
    float d0, d1, a = 0.f;                                                    \
    d0 = fmaf(ekk[0].x, f0[jj].x, 1.0f); d1 = fmaf(ekk[0].y, f0[jj].y, 1.0f); \
    a += (v0.x * d1 + v0.y * d0) * __builtin_amdgcn_rcpf(d0 * d1);            \
    d0 = fmaf(ekk[1].x, f0[jj].z, 1.0f); d1 = fmaf(ekk[1].y, f0[jj].w, 1.0f); \
    a += (v0.z * d1 + v0.w * d0) * __builtin_amdgcn_rcpf(d0 * d1);            \
    d0 = fmaf(ekk[2].x, f1[jj].x, 1.0f); d1 = fmaf(ekk[2].y, f1[jj].y, 1.0f); \
    a += (v1.x * d1 + v1.y * d0) * __builtin_amdgcn_rcpf(d0 * d1);            \
    d0 = fmaf(ekk[3].x, f1[jj].z, 1.0f); d1 = fmaf(ekk[3].y, f1[jj].w, 1.0f); \
    a += (v1.z * d1 + v1.w * d0) * __builtin_amdgcn_rcpf(d0 * d1);            \
    acc += a;                                                                 \
  }

  LOADE2(eka, Ep[0], 0);               // prologue: (kc=0, tile 0)
  for (int kc = 0; kc < 16; ++kc) {
    float4 f0[4], f1[4];               // block-uniform -> SGPR
    const float4* fpc = Fp + kc * 2;
    #pragma unroll
    for (int j = 0; j < 4; ++j) {
      f0[j] = fpc[j * 32];
      f1[j] = fpc[j * 32 + 1];
    }
    float4 v0 = vp[kc * 2], v1 = vp[kc * 2 + 1];
    // copy-free ping-pong: tiles 0,2 in eka; 1,3 in ekb (within a kc)
    LOADE2(ekb, Ep[1], kc * 512);
    #pragma unroll
    for (int j = 0; j < 4; ++j) UNIT(s[0][j], eka, j)
    LOADE2(eka, Ep[2], kc * 512);
    #pragma unroll
    for (int j = 0; j < 4; ++j) UNIT(s[1][j], ekb, j)
    LOADE2(ekb, Ep[3], kc * 512);
    #pragma unroll
    for (int j = 0; j < 4; ++j) UNIT(s[2][j], eka, j)
    LOADE2(eka, Ep[0], (kc + 1) * 512);  // kc=15: reads next tile's base (max index
    #pragma unroll                        // 232 < 256, in-bounds, value never used)
    for (int j = 0; j < 4; ++j) UNIT(s[3][j], ekb, j)
  }
  #pragma unroll
  for (int it = 0; it < 4; ++it) {
    int t = (w + 8 * it) * 64 + lane;
    S[0 * 2048 + t] = V1 - 2.0f * s[it][0];  // bank = lane%32: 2-way (free)
    S[1 * 2048 + t] = V1 - 2.0f * s[it][1];
    S[2 * 2048 + t] = V1 - 2.0f * s[it][2];
    S[3 * 2048 + t] = V1 - 2.0f * s[it][3];
  }
  __syncthreads();

  // ---- phase 2: softmax per j-row (2 waves per j); e overwrites S in place ----
  int j = w >> 1, half = w & 1;
  int tb2 = half * 1024 + lane;
  float x[16];
  #pragma unroll
  for (int q = 0; q < 16; ++q) x[q] = S[j * 2048 + tb2 + q * 64];
  float m = x[0];
  #pragma unroll
  for (int q = 1; q < 16; ++q) m = fmaxf(m, x[q]);
  #pragma unroll
  for (int off = 32; off > 0; off >>= 1) m = fmaxf(m, __shfl_xor(m, off));
  if (lane == 0) red[w] = m;
  __syncthreads();                             // also: all raw-S reads complete
  m = fmaxf(red[j * 2], red[j * 2 + 1]);
  const float L2E = 1.4426950408889634f;
  float sum = 0.f;
  #pragma unroll
  for (int q = 0; q < 16; ++q) {
    x[q] = __builtin_amdgcn_exp2f((x[q] - m) * L2E);
    sum += x[q];
  }
  #pragma unroll
  for (int off = 32; off > 0; off >>= 1) sum += __shfl_xor(sum, off);
  if (lane == 0) red[8 + w] = sum;
  __syncthreads();
  float inv = 1.0f / (red[8 + j * 2] + red[8 + j * 2 + 1]);
  float* orow = oute + (size_t)(b * TD + j0 + j) * TE;
  #pragma unroll
  for (int q = 0; q < 16; ++q) {
    float e = x[q] * inv;
    int t = tb2 + q * 64;
    orow[t] = e;                               // coalesced 256 B/instr
    S[j * 2048 + t] = e;                       // in place: same slot it read
  }
  __syncthreads();

  // ---- phase 3: c[j][h] = sum_t e[j][t]*enc[t][h]; 16 slices x 128 t, pipelined ----
  int hq = tid & 31, slice = tid >> 5;         // h = hq*4; t in [slice*128, ...+128)
  const float* encp = enc + ((size_t)b * TE + slice * 128) * H + hq * 4;
  const float* Se = S + slice * 128;           // + j*2048 + t (b128 broadcast)
  float4 ac0{0,0,0,0}, ac1{0,0,0,0}, ac2{0,0,0,0}, ac3{0,0,0,0};
  float4 evA0, evA1, evA2, evA3, evB0, evB1, evB2, evB3;

#define LOADENC(d0, d1, d2, d3, t0)                         \
  d0 = *(const float4*)(encp + (size_t)(t0 + 0) * H);       \
  d1 = *(const float4*)(encp + (size_t)(t0 + 1) * H);       \
  d2 = *(const float4*)(encp + (size_t)(t0 + 2) * H);       \
  d3 = *(const float4*)(encp + (size_t)(t0 + 3) * H);

#define GROUP(t0, ex, ey, ez, ew)                                            \
  {                                                                          \
    float4 E0 = *(const float4*)&Se[0 * 2048 + (t0)];                        \
    float4 E1 = *(const float4*)&Se[1 * 2048 + (t0)];                        \
    float4 E2 = *(const float4*)&Se[2 * 2048 + (t0)];                        \
    float4 E3 = *(const float4*)&Se[3 * 2048 + (t0)];                        \
    FMA4(ac0, E0.x, ex); FMA4(ac0, E0.y, ey); FMA4(ac0, E0.z, ez); FMA4(ac0, E0.w, ew); \
    FMA4(ac1, E1.x, ex); FMA4(ac1, E1.y, ey); FMA4(ac1, E1.z, ez); FMA4(ac1, E1.w, ew); \
    FMA4(ac2, E2.x, ex); FMA4(ac2, E2.y, ey); FMA4(ac2, E2.z, ez); FMA4(ac2, E2.w, ew); \
    FMA4(ac3, E3.x, ex); FMA4(ac3, E3.y, ey); FMA4(ac3, E3.z, ez); FMA4(ac3, E3.w, ew); \
  }

  LOADENC(evA0, evA1, evA2, evA3, 0);
  #pragma unroll
  for (int tb = 0; tb < 128; tb += 8) {
    LOADENC(evB0, evB1, evB2, evB3, tb + 4);
    GROUP(tb, evA0, evA1, evA2, evA3);
    if (tb < 120) { LOADENC(evA0, evA1, evA2, evA3, tb + 8); }
    GROUP(tb + 4, evB0, evB1, evB2, evB3);
  }
  __syncthreads();                             // all e-reads done; reuse S for partials
  if (slice < 8) {                             // wave-uniform (waves 0-3)
    float* dst = &S[slice * 512 + hq * 4];
    *(float4*)(dst + 0 * 128) = ac0; *(float4*)(dst + 1 * 128) = ac1;
    *(float4*)(dst + 2 * 128) = ac2; *(float4*)(dst + 3 * 128) = ac3;
  }
  __syncthreads();
  if (slice >= 8) {                            // waves 4-7: read-modify-add
    float* dst = &S[(slice - 8) * 512 + hq * 4];
    #define RMW(J, AC) { float4 p = *(float4*)(dst + J * 128); \
      p.x += AC.x; p.y += AC.y; p.z += AC.z; p.w += AC.w; \
      *(float4*)(dst + J * 128) = p; }
    RMW(0, ac0) RMW(1, ac1) RMW(2, ac2) RMW(3, ac3)
    #undef RMW
  }
  __syncthreads();
  float r = 0.f;
  #pragma unroll
  for (int sl = 0; sl < 8; ++sl) r += S[sl * 512 + tid];   // stride-1, conflict-free
  outc[(size_t)(b * TD + j0 + (tid >> 7)) * H + (tid & 127)] = r;
}

extern "C" void kernel_launch(void* const* d_in, const int* in_sizes, int n_in,
                              void* d_out, int out_size, void* d_ws, size_t ws_size,
                              hipStream_t stream) {
  (void)in_sizes; (void)n_in; (void)out_size; (void)ws_size;
  const float* enc = (const float*)d_in[0];
  const float* dec = (const float*)d_in[1];
  const float* Wa  = (const float*)d_in[2];
  const float* Ua  = (const float*)d_in[3];
  const float* Va  = (const float*)d_in[4];

  float* ws  = (float*)d_ws;
  float* EgT = ws;                                   // 8 MB  E tiled [b][tb][k2][tl][2]
  float* Fg  = EgT + (size_t)B * TE * H;             // 1 MB  F [b][j][k]
  float* outc = (float*)d_out;                       // c [B,TD,H] fp32
  float* oute = outc + (size_t)B * TD * H;           // e [B,TD,TE] fp32

  proj_kernel<<<dim3(1152), 256, 0, stream>>>(enc, dec, Wa, Ua, EgT, Fg);
  fused_kernel<<<dim3(512), 512, 0, stream>>>(EgT, Fg, Va, enc, oute, outc);
}